// Round 4
// baseline (614.383 us; speedup 1.0000x reference)
//
#include <hip/hip_runtime.h>

#define DIM_IN 128
#define DIM_HID 256
#define DIM_OUT 128
#define N_DIST 1024
#define NCHUNK 64       // contiguous node chunks
#define NQ 8            // dim slices (16 dims = 64 B = 1 cache line each)
#define DSUB 16         // dims per slice

// ws layout (bytes):
// [0, 2MB):        zone32[500000] int32
// [2MB, 2MB+32MB): partial[NCHUNK][NQ][N_DIST][DSUB] float
//
// No sort, no global atomics, no random reads: x is streamed sequentially;
// the segment-scatter happens in LDS (dense 1024x16 fp32 table per block).

__global__ __launch_bounds__(256)
void zoneconv_kernel(const int* __restrict__ zone_raw, int n,
                     int* __restrict__ zone32) {
    __shared__ int s_is64;
    const int t = threadIdx.x;
    if (t < 64) {
        // int64 zone_lst => high 32-bit words all zero (values < 1024).
        bool hi_zero = (zone_raw[2 * t + 1] == 0);
        unsigned long long m = __ballot(hi_zero);
        if (t == 0) s_is64 = (m == ~0ull) ? 1 : 0;
    }
    __syncthreads();
    const int is64 = s_is64;
    const long long* z64 = (const long long*)zone_raw;
    int i = blockIdx.x * 256 + t;
    const int stride = gridDim.x * 256;
    for (; i < n; i += stride)
        zone32[i] = is64 ? (int)z64[i] : zone_raw[i];
}

// Block (c,q): stream nodes [beg,end), dims [16q,16q+16) -> LDS table,
// then dump the 64 KB table to partial[c][q].
__global__ __launch_bounds__(1024)
void phase1_kernel(const float* __restrict__ x, const int* __restrict__ zone32,
                   int n, float* __restrict__ partial) {
    __shared__ float lhead[N_DIST * DSUB];   // 64 KB
    const int t = threadIdx.x;
    const int c = blockIdx.x >> 3;
    const int q = blockIdx.x & 7;

    float4* lh4 = (float4*)lhead;
#pragma unroll
    for (int i = 0; i < (N_DIST * DSUB / 4) / 1024; i++)
        lh4[t + i * 1024] = make_float4(0.f, 0.f, 0.f, 0.f);
    __syncthreads();

    const int chunk = (n + NCHUNK - 1) / NCHUNK;
    const int beg = c * chunk;
    const int end = min(n, beg + chunk);
    const int node_off = t >> 4;      // 0..63: 4 consecutive nodes per wave
    const int j = t & 15;             // dim within slice
    const int dim = q * DSUB + j;

    int i = beg + node_off;
    // unroll-2 by hand so 2 loads are in flight ahead of the LDS atomics
    for (; i + 64 < end; i += 128) {
        int z0 = zone32[i];
        int z1 = zone32[i + 64];
        float v0 = x[(size_t)i * DIM_IN + dim];
        float v1 = x[(size_t)(i + 64) * DIM_IN + dim];
        atomicAdd(&lhead[z0 * DSUB + j], v0);
        atomicAdd(&lhead[z1 * DSUB + j], v1);
    }
    for (; i < end; i += 64) {
        int z = zone32[i];
        float v = x[(size_t)i * DIM_IN + dim];
        atomicAdd(&lhead[z * DSUB + j], v);
    }
    __syncthreads();

    float4* dst = (float4*)(partial + ((size_t)(c * NQ + q)) * (N_DIST * DSUB));
#pragma unroll
    for (int i2 = 0; i2 < (N_DIST * DSUB / 4) / 1024; i2++)
        dst[t + i2 * 1024] = lh4[t + i2 * 1024];
}

// One block per district: reduce 64 chunk-partials -> head[128], then
// fused MLP: relu -> @w1+b1 -> relu -> @w2+b2.
__global__ __launch_bounds__(256)
void phase2_kernel(const float* __restrict__ partial,
                   const float* __restrict__ w1, const float* __restrict__ b1,
                   const float* __restrict__ w2, const float* __restrict__ b2,
                   float* __restrict__ out) {
    const int d = blockIdx.x;
    const int t = threadIdx.x;
    const int dim = t & 127;
    const int half = t >> 7;          // 0 or 1: chunks [0,32) / [32,64)
    const int q = dim >> 4;
    const int j = dim & 15;

    float s = 0.f;
    const float* src = partial + (size_t)q * (N_DIST * DSUB) + d * DSUB + j;
#pragma unroll 8
    for (int c = half * 32; c < half * 32 + 32; c++)
        s += src[(size_t)c * NQ * (N_DIST * DSUB)];

    __shared__ float htmp[2][DIM_IN];
    __shared__ float hrelu[DIM_IN];
    htmp[half][dim] = s;
    __syncthreads();
    if (t < DIM_IN) hrelu[t] = fmaxf(htmp[0][t] + htmp[1][t], 0.f);
    __syncthreads();

    // h1[t] = relu(b1[t] + sum_k hrelu[k] * w1[k,t]);  w1 row-major [128,256]
    float s1 = b1[t];
#pragma unroll 8
    for (int k = 0; k < DIM_IN; k++)
        s1 = fmaf(hrelu[k], w1[k * DIM_HID + t], s1);
    __shared__ float h1[DIM_HID];
    h1[t] = fmaxf(s1, 0.f);
    __syncthreads();

    // out[d,t] = b2[t] + sum_j h1[j] * w2[j,t];  w2 row-major [256,128]
    if (t < DIM_OUT) {
        float s2 = b2[t];
#pragma unroll 8
        for (int jj = 0; jj < DIM_HID; jj++)
            s2 = fmaf(h1[jj], w2[jj * DIM_OUT + t], s2);
        out[d * DIM_OUT + t] = s2;
    }
}

extern "C" void kernel_launch(void* const* d_in, const int* in_sizes, int n_in,
                              void* d_out, int out_size, void* d_ws, size_t ws_size,
                              hipStream_t stream) {
    const float* x    = (const float*)d_in[0];
    const int*   zone = (const int*)d_in[1];
    const float* w1   = (const float*)d_in[2];
    const float* b1   = (const float*)d_in[3];
    const float* w2   = (const float*)d_in[4];
    const float* b2   = (const float*)d_in[5];
    float* out = (float*)d_out;
    const int n = in_sizes[0] / DIM_IN;   // 500000 nodes

    char* ws = (char*)d_ws;
    int*   zone32  = (int*)(ws);
    float* partial = (float*)(ws + (2u << 20));

    zoneconv_kernel<<<512, 256, 0, stream>>>(zone, n, zone32);
    phase1_kernel<<<NCHUNK * NQ, 1024, 0, stream>>>(x, zone32, n, partial);
    phase2_kernel<<<N_DIST, 256, 0, stream>>>(partial, w1, b1, w2, b2, out);
}